// Round 2
// baseline (8092.547 us; speedup 1.0000x reference)
//
#include <hip/hip_runtime.h>
#include <hip/hip_bf16.h>

#define B_   64
#define T_   1024
#define D_   512
#define H_   512
#define G4H  2048
#define K_   1024

typedef __bf16 bf16x8 __attribute__((ext_vector_type(8)));
typedef float  f32x4  __attribute__((ext_vector_type(4)));
typedef int    i32x4  __attribute__((ext_vector_type(4)));

#define SENT 0x7FC07FC0   // two bf16 qNaNs packed; computed h is always finite

// workspace layout (bytes)
#define OFF_XT  0ull                                            // x transposed (T,B,D) bf16: 64 MiB
#define OFF_H1  (OFF_XT + (unsigned long long)T_*B_*D_*2)       // h1 history (T,B,H) bf16
#define OFF_H2  (OFF_H1 + (unsigned long long)T_*B_*H_*2)       // h2 history (T,B,H) bf16
#define OFF_WP  (OFF_H2 + (unsigned long long)T_*B_*H_*2)       // W' (L,4H,K) bf16 = [Wx|Wh]
#define OFF_ZB  (OFF_WP + (unsigned long long)2*G4H*K_*2)       // 16 KiB zeros (h_{-1})
#define OUT_HN  33554432ull                                     // B*T*H

// ---------------- prep: transpose+cast x, pack+cast weights, poison h ------
__global__ void prep_kernel(const float* __restrict__ x, const float* __restrict__ Wx,
                            const float* __restrict__ Wh, unsigned char* __restrict__ ws)
{
    unsigned tid = blockIdx.x * 256u + threadIdx.x;   // grid = 16384*256 = 4,194,304
    __hip_bfloat16* xT = (__hip_bfloat16*)(ws + OFF_XT);
    __hip_bfloat16* Wp = (__hip_bfloat16*)(ws + OFF_WP);

    {   // x (B,T,D) fp32 -> xT (T,B,D) bf16, 8 elems/thread (exactly covers 33,554,432)
        unsigned base = tid * 8u;
        unsigned d  = base & (D_ - 1);
        unsigned bt = base >> 9;            // b*T + t
        unsigned t  = bt & (T_ - 1);
        unsigned b  = bt >> 10;
        const float* src = x + base;
        __hip_bfloat16* dst = xT + ((unsigned long long)t * B_ + b) * D_ + d;
        float4 f0 = *(const float4*)(src);
        float4 f1 = *(const float4*)(src + 4);
        dst[0] = __float2bfloat16(f0.x); dst[1] = __float2bfloat16(f0.y);
        dst[2] = __float2bfloat16(f0.z); dst[3] = __float2bfloat16(f0.w);
        dst[4] = __float2bfloat16(f1.x); dst[5] = __float2bfloat16(f1.y);
        dst[6] = __float2bfloat16(f1.z); dst[7] = __float2bfloat16(f1.w);
    }
    {   // W'[l][r][k] = k<512 ? Wx[l][r][k] : Wh[l][r][k-512]  (one elem/thread, exact cover)
        unsigned i = tid;
        unsigned k = i & (K_ - 1);
        unsigned r = (i >> 10) & (G4H - 1);
        unsigned l = i >> 21;
        float v = (k < D_) ? Wx[((unsigned long long)l * G4H + r) * D_ + k]
                           : Wh[((unsigned long long)l * G4H + r) * H_ + (k - D_)];
        Wp[i] = __float2bfloat16(v);
    }
    {   // poison h1+h2 (128 MiB) with the sentinel: 32 B/thread, exact cover
        uint4 s; s.x = s.y = s.z = s.w = SENT;
        uint4* p = (uint4*)(ws + OFF_H1) + (unsigned long long)tid * 2u;
        p[0] = s; p[1] = s;
    }
    if (tid < 8192u) ((__hip_bfloat16*)(ws + OFF_ZB))[tid] = __float2bfloat16(0.f);
}

__device__ __forceinline__ unsigned bf16_bits(float f)
{
    union { __hip_bfloat16 h; unsigned short u; } c;
    c.h = __float2bfloat16(f);
    return (unsigned)c.u;
}

// L1+L2-bypassing 16B load (fresh from the device coherence point every issue)
#define PLD(dst, base, OFFS) \
    asm volatile("global_load_dwordx4 %0, %1, off offset:" OFFS " sc0 sc1" \
                 : "=v"(dst) : "v"(base))

#define POLL16(buf, base)                                  \
    PLD(buf[0],  base, "0");   PLD(buf[1],  base, "64");   \
    PLD(buf[2],  base, "128"); PLD(buf[3],  base, "192");  \
    PLD(buf[4],  base, "256"); PLD(buf[5],  base, "320");  \
    PLD(buf[6],  base, "384"); PLD(buf[7],  base, "448");  \
    PLD(buf[8],  base, "512"); PLD(buf[9],  base, "576");  \
    PLD(buf[10], base, "640"); PLD(buf[11], base, "704");  \
    PLD(buf[12], base, "768"); PLD(buf[13], base, "832");  \
    PLD(buf[14], base, "896"); PLD(buf[15], base, "960")

template<int CNT>
__device__ __forceinline__ int frag_ok(const i32x4* v)
{
    int ok = 1;
#pragma unroll
    for (int i = 0; i < CNT; ++i)
        ok &= (v[i][0] != (int)SENT) & (v[i][1] != (int)SENT) &
              (v[i][2] != (int)SENT) & (v[i][3] != (int)SENT);
    return ok;
}

// ---------------- persistent pipelined sLSTM --------------------------------
// grid = 512 blocks x 64 threads. chain = blk&7: chains 0-3 = layer0 batch
// groups, 4-7 = layer1. w = blk>>3 owns hidden units [w*8, w*8+8).
// Sync: NONE beyond the data itself. h buffers are pre-poisoned with a bf16
// qNaN sentinel; producers fire sc1 write-through u32 stores (atomic pack of
// 2 bf16) and continue; consumers poll the exact fragments they need with
// sc0+sc1 (L1+L2 bypass) dwordx4 loads until sentinel-free. The successful
// poll IS the MFMA operand load — zero extra hops.
__launch_bounds__(64, 1)
__global__ void slstm_persist(const float* __restrict__ bx, const float* __restrict__ bh,
                              const float* __restrict__ bext, unsigned char* ws,
                              float* __restrict__ out)
{
    const int lane = threadIdx.x;
    const int n    = lane & 15;
    const int quad = lane >> 4;
    const int blk  = blockIdx.x;
    const int chain = blk & 7;
    const int w     = blk >> 3;          // 0..63
    const int layer = chain >> 2;
    const int g     = chain & 3;
    const int hid_base   = w * 8;
    const int batch_base = g * 16;

    const __hip_bfloat16* xT = (const __hip_bfloat16*)(ws + OFF_XT);
    __hip_bfloat16* h1buf = (__hip_bfloat16*)(ws + OFF_H1);
    __hip_bfloat16* h2buf = (__hip_bfloat16*)(ws + OFF_H2);
    const __hip_bfloat16* Wp = (const __hip_bfloat16*)(ws + OFF_WP);
    const __hip_bfloat16* zb = (const __hip_bfloat16*)(ws + OFF_ZB);

    // gate-row mapping: tile0 = [i(hid 0..7) | o(hid 0..7)], tile1 = [f | u]
    const int r0 = (n < 8) ? (hid_base + n) : (2*H_ + hid_base + n - 8);
    const int r1 = (n < 8) ? (H_ + hid_base + n) : (3*H_ + hid_base + n - 8);
    const float bias0 = bx[layer*G4H + r0] + bh[layer*G4H + r0] + bext[layer*G4H + r0];
    const float bias1 = bx[layer*G4H + r1] + bh[layer*G4H + r1] + bext[layer*G4H + r1];

    // preload weights into regs: 64 fragments -> AGPR side of the unified file
    const __hip_bfloat16* Wl = Wp + (unsigned long long)layer * G4H * K_;
    bf16x8 B0[32], B1[32];
#pragma unroll
    for (int kt = 0; kt < 32; ++kt) {
        B0[kt] = *(const bf16x8*)(Wl + (unsigned long long)r0 * K_ + kt*32 + quad*8);
        B1[kt] = *(const bf16x8*)(Wl + (unsigned long long)r1 * K_ + kt*32 + quad*8);
    }

    const __hip_bfloat16* xin  = (layer == 0) ? xT : h1buf;   // K 0..511 source
    __hip_bfloat16*       hout = (layer == 0) ? h1buf : h2buf; // own h history (K 512..1023 src)

    float cst[4] = {0.f,0.f,0.f,0.f}, nst[4] = {0.f,0.f,0.f,0.f};

#pragma unroll 1
    for (int t = 0; t < T_; ++t) {
        bf16x8 a[32];
        const __hip_bfloat16* Ax = xin + ((unsigned long long)t * B_ + batch_base + n) * D_ + quad*8;
        const __hip_bfloat16* Ah = hout + ((unsigned long long)(t-1) * B_ + batch_base + n) * H_ + quad*8;

        if (layer == 0) {
            // x is static: plain cached loads, issued before the poll
#pragma unroll
            for (int kt = 0; kt < 16; ++kt) a[kt] = *(const bf16x8*)(Ax + kt*32);
            if (t == 0) {
#pragma unroll
                for (int kt = 0; kt < 16; ++kt)
                    a[16+kt] = *(const bf16x8*)(zb + n * H_ + quad*8 + kt*32);
            } else {
                i32x4 hb[16];
                for (;;) {
                    POLL16(hb, Ah);
                    asm volatile("s_waitcnt vmcnt(0)" ::: "memory");
                    __builtin_amdgcn_sched_barrier(0);
                    if (__all(frag_ok<16>(hb))) break;
                }
#pragma unroll
                for (int kt = 0; kt < 16; ++kt) a[16+kt] = __builtin_bit_cast(bf16x8, hb[kt]);
            }
        } else {
            if (t == 0) {
                i32x4 xb[16];
                for (;;) {
                    POLL16(xb, Ax);
                    asm volatile("s_waitcnt vmcnt(0)" ::: "memory");
                    __builtin_amdgcn_sched_barrier(0);
                    if (__all(frag_ok<16>(xb))) break;
                }
#pragma unroll
                for (int kt = 0; kt < 16; ++kt) a[kt] = __builtin_bit_cast(bf16x8, xb[kt]);
#pragma unroll
                for (int kt = 0; kt < 16; ++kt)
                    a[16+kt] = *(const bf16x8*)(zb + n * H_ + quad*8 + kt*32);
            } else {
                i32x4 xb[16], hb[16];
                for (;;) {
                    POLL16(xb, Ax);
                    POLL16(hb, Ah);
                    asm volatile("s_waitcnt vmcnt(0)" ::: "memory");
                    __builtin_amdgcn_sched_barrier(0);
                    int ok = frag_ok<16>(xb) & frag_ok<16>(hb);
                    if (__all(ok)) break;
                }
#pragma unroll
                for (int kt = 0; kt < 16; ++kt) a[kt]    = __builtin_bit_cast(bf16x8, xb[kt]);
#pragma unroll
                for (int kt = 0; kt < 16; ++kt) a[16+kt] = __builtin_bit_cast(bf16x8, hb[kt]);
            }
        }

        f32x4 acc0 = {0.f,0.f,0.f,0.f}, acc1 = {0.f,0.f,0.f,0.f};
#pragma unroll
        for (int kt = 0; kt < 32; ++kt) {
            acc0 = __builtin_amdgcn_mfma_f32_16x16x32_bf16(a[kt], B0[kt], acc0, 0, 0, 0);
            acc1 = __builtin_amdgcn_mfma_f32_16x16x32_bf16(a[kt], B1[kt], acc1, 0, 0, 0);
        }

        float hv[4];
#pragma unroll
        for (int r = 0; r < 4; ++r) {
            float v0 = acc0[r] + bias0;          // i | o pre-activation
            float v1 = acc1[r] + bias1;          // f | u pre-activation
            float act0 = 1.f / (1.f + __expf(-v0));        // sigmoid (i and o)
            float pre  = (n < 8) ? -v1 : -2.f*v1;
            float s    = 1.f / (1.f + __expf(pre));
            float act1 = (n < 8) ? s : (2.f*s - 1.f);      // f: sigmoid, u: tanh=2σ(2x)-1
            float o_ = __shfl_xor(act0, 8);      // lanes n<8 receive sigmoid(o)
            float u_ = __shfl_xor(act1, 8);      // lanes n<8 receive tanh(u)
            float ci = act1 * cst[r] + act0 * u_;              // f*c + i*u
            float ni = fminf(fmaxf(act1 * nst[r] + act0, 1e-6f), 1e6f);
            cst[r] = ci; nst[r] = ni;
            float ratio = ci / ni;               // |ratio| <= 1 by induction
            float e2 = __expf(-2.f * ratio);
            float th = (1.f - e2) / (1.f + e2);  // tanh(ratio)
            hv[r] = o_ * th;

            // publish immediately: pack bf16 pair (hid n, n+1) into u32, sc1
            // write-through (agent scope) — u32 granularity matches the
            // consumer's sentinel check, so no tearing, no fence, no flag.
            unsigned mybits = bf16_bits(hv[r]);
            unsigned other  = (unsigned)__shfl_xor((int)mybits, 1);
            if ((n & 1) == 0 && n < 8) {
                const int b = batch_base + quad*4 + r;
                unsigned pack = (mybits & 0xffffu) | (other << 16);
                unsigned* p = (unsigned*)(hout + ((unsigned long long)t * B_ + b) * H_ + hid_base + n);
                __hip_atomic_store(p, pack, __ATOMIC_RELAXED, __HIP_MEMORY_SCOPE_AGENT);
            }
        }

        if (n < 8) {
            const int hid = hid_base + n;
            if (layer == 1) {
#pragma unroll
                for (int r = 0; r < 4; ++r) {
                    const int b = batch_base + quad*4 + r;
                    out[((unsigned long long)b * T_ + t) * H_ + hid] = hv[r];  // plain (kernel-end flush)
                }
            }
            if (t == T_ - 1) {
#pragma unroll
                for (int r = 0; r < 4; ++r) {
                    const int b = batch_base + quad*4 + r;
                    unsigned long long so = OUT_HN + (unsigned long long)layer*32768ull
                                          + (unsigned long long)b*H_ + hid;
                    out[so]            = hv[r];   // hN
                    out[so +  65536ull] = cst[r]; // cN
                    out[so + 131072ull] = nst[r]; // nN
                }
            }
        }
        // no trailing fence: stores drain while this WG begins its next poll
    }
}

extern "C" void kernel_launch(void* const* d_in, const int* in_sizes, int n_in,
                              void* d_out, int out_size, void* d_ws, size_t ws_size,
                              hipStream_t stream)
{
    const float* x    = (const float*)d_in[0];
    const float* Wx   = (const float*)d_in[1];
    const float* bx   = (const float*)d_in[2];
    const float* Wh   = (const float*)d_in[3];
    const float* bh   = (const float*)d_in[4];
    const float* bext = (const float*)d_in[5];
    float* out = (float*)d_out;
    unsigned char* ws = (unsigned char*)d_ws;
    // needs ~200 MiB of workspace (xT 64M + h1 64M + h2 64M + W' 8M + zb)

    prep_kernel<<<16384, 256, 0, stream>>>(x, Wx, Wh, ws);
    slstm_persist<<<512, 64, 0, stream>>>(bx, bh, bext, ws, out);
}

// Round 4
// 7863.726 us; speedup vs baseline: 1.0291x; 1.0291x over previous
//
#include <hip/hip_runtime.h>
#include <hip/hip_bf16.h>

#define B_   64
#define T_   1024
#define D_   512
#define H_   512
#define G4H  2048
#define K_   1024

typedef __bf16 bf16x8 __attribute__((ext_vector_type(8)));
typedef float  f32x4  __attribute__((ext_vector_type(4)));

// workspace layout (bytes)
#define OFF_XT  0ull                                            // x transposed (T,B,D) bf16: 64 MiB
#define OFF_H1  (OFF_XT + (unsigned long long)T_*B_*D_*2)       // h1 history (T,B,H) bf16
#define OFF_H2  (OFF_H1 + (unsigned long long)T_*B_*H_*2)       // h2 history (T,B,H) bf16
#define OFF_WP  (OFF_H2 + (unsigned long long)T_*B_*H_*2)       // W' (L,4H,K) bf16 = [Wx|Wh]
#define OFF_ZB  (OFF_WP + (unsigned long long)2*G4H*K_*2)       // 16 KiB zeros (h_{-1})
#define OFF_FLG (OFF_ZB + 16384ull)                             // flags 16 KiB: int flags[8][16]
#define OUT_HN  33554432ull                                     // B*T*H

// ---------------- prep: transpose+cast x, pack+cast weights, zero flags ----
__global__ void prep_kernel(const float* __restrict__ x, const float* __restrict__ Wx,
                            const float* __restrict__ Wh, unsigned char* __restrict__ ws)
{
    unsigned tid = blockIdx.x * 256u + threadIdx.x;   // grid = 16384*256 = 4,194,304
    __hip_bfloat16* xT = (__hip_bfloat16*)(ws + OFF_XT);
    __hip_bfloat16* Wp = (__hip_bfloat16*)(ws + OFF_WP);

    {   // x (B,T,D) fp32 -> xT (T,B,D) bf16, 8 elems/thread (exactly covers 33,554,432)
        unsigned base = tid * 8u;
        unsigned d  = base & (D_ - 1);
        unsigned bt = base >> 9;            // b*T + t
        unsigned t  = bt & (T_ - 1);
        unsigned b  = bt >> 10;
        const float* src = x + base;
        __hip_bfloat16* dst = xT + ((unsigned long long)t * B_ + b) * D_ + d;
        float4 f0 = *(const float4*)(src);
        float4 f1 = *(const float4*)(src + 4);
        dst[0] = __float2bfloat16(f0.x); dst[1] = __float2bfloat16(f0.y);
        dst[2] = __float2bfloat16(f0.z); dst[3] = __float2bfloat16(f0.w);
        dst[4] = __float2bfloat16(f1.x); dst[5] = __float2bfloat16(f1.y);
        dst[6] = __float2bfloat16(f1.z); dst[7] = __float2bfloat16(f1.w);
    }
    {   // W'[l][r][k] = k<512 ? Wx[l][r][k] : Wh[l][r][k-512]  (one elem/thread, exact cover)
        unsigned i = tid;
        unsigned k = i & (K_ - 1);
        unsigned r = (i >> 10) & (G4H - 1);
        unsigned l = i >> 21;
        float v = (k < D_) ? Wx[((unsigned long long)l * G4H + r) * D_ + k]
                           : Wh[((unsigned long long)l * G4H + r) * H_ + (k - D_)];
        Wp[i] = __float2bfloat16(v);
    }
    if (tid < 8192u) ((__hip_bfloat16*)(ws + OFF_ZB))[tid] = __float2bfloat16(0.f);
    if (tid < 4096u) ((int*)(ws + OFF_FLG))[tid] = 0;
}

__device__ __forceinline__ unsigned bf16_bits(float f)
{
    union { __hip_bfloat16 h; unsigned short u; } c;
    c.h = __float2bfloat16(f);
    return (unsigned)c.u;
}

// ---------------- persistent pipelined sLSTM --------------------------------
// grid = 128 blocks x 256 threads (4 waves). chain = blk&7: chains 0-3 = layer0
// batch groups, 4-7 = layer1. w2 = blk>>3 in [0,16); wave wv owns hidden units
// [w2*32 + wv*8, +8). Barrier per chain is 16 WGs wide: one flag per WG, all
// 16 flags in ONE cache line. Explicit vmcnt(0) + __syncthreads() is the
// store-ack for all 4 waves; tid0 then publishes the flag. Data loads stay
// plain/cached: the 4 waves of a WG share L1 for the same x/h tiles, the 16
// WGs of a chain share the XCD L2 (chain = blk&7 swizzle; perf-only
// assumption, correctness is all device-scope/L3). Spins carry s_sleep(1)
// backoff (~27 ns) to bound poll traffic at the coherence point.
__launch_bounds__(256, 1)
__global__ void slstm_persist(const float* __restrict__ bx, const float* __restrict__ bh,
                              const float* __restrict__ bext, unsigned char* ws,
                              float* __restrict__ out)
{
    const int tid  = threadIdx.x;
    const int lane = tid & 63;
    const int wv   = tid >> 6;           // wave 0..3
    const int n    = lane & 15;
    const int quad = lane >> 4;
    const int blk  = blockIdx.x;
    const int chain = blk & 7;
    const int w2    = blk >> 3;          // 0..15
    const int layer = chain >> 2;
    const int g     = chain & 3;
    const int hid_base   = w2 * 32 + wv * 8;
    const int batch_base = g * 16;

    const __hip_bfloat16* xT = (const __hip_bfloat16*)(ws + OFF_XT);
    __hip_bfloat16* h1buf = (__hip_bfloat16*)(ws + OFF_H1);
    __hip_bfloat16* h2buf = (__hip_bfloat16*)(ws + OFF_H2);
    const __hip_bfloat16* Wp = (const __hip_bfloat16*)(ws + OFF_WP);
    const __hip_bfloat16* zb = (const __hip_bfloat16*)(ws + OFF_ZB);
    int* flags = (int*)(ws + OFF_FLG);
    int* myf = flags + chain * 16;       // this chain's 16 per-WG flags (one line)
    int* prf = flags + g * 16;           // layer-0 chain of same batch group

    // gate-row mapping: tile0 = [i(hid 0..7) | o(hid 0..7)], tile1 = [f | u]
    const int r0 = (n < 8) ? (hid_base + n) : (2*H_ + hid_base + n - 8);
    const int r1 = (n < 8) ? (H_ + hid_base + n) : (3*H_ + hid_base + n - 8);
    const float bias0 = bx[layer*G4H + r0] + bh[layer*G4H + r0] + bext[layer*G4H + r0];
    const float bias1 = bx[layer*G4H + r1] + bh[layer*G4H + r1] + bext[layer*G4H + r1];

    // preload weights into regs: 64 fragments per wave (wave-private reg file)
    const __hip_bfloat16* Wl = Wp + (unsigned long long)layer * G4H * K_;
    bf16x8 B0[32], B1[32];
#pragma unroll
    for (int kt = 0; kt < 32; ++kt) {
        B0[kt] = *(const bf16x8*)(Wl + (unsigned long long)r0 * K_ + kt*32 + quad*8);
        B1[kt] = *(const bf16x8*)(Wl + (unsigned long long)r1 * K_ + kt*32 + quad*8);
    }

    const __hip_bfloat16* xin  = (layer == 0) ? xT : h1buf;   // K 0..511 source
    __hip_bfloat16*       hout = (layer == 0) ? h1buf : h2buf; // own h history (K 512..1023 src)

    float cst[4] = {0.f,0.f,0.f,0.f}, nst[4] = {0.f,0.f,0.f,0.f};

    // persistent x-operand regs; layer0 pre-fills t=0 (static data)
    bf16x8 axv[16];
    if (layer == 0) {
        const __hip_bfloat16* Ax0 = xin + ((unsigned long long)(batch_base + n)) * D_ + quad*8;
#pragma unroll
        for (int kt = 0; kt < 16; ++kt) axv[kt] = *(const bf16x8*)(Ax0 + kt*32);
    }

#pragma unroll 1
    for (int t = 0; t < T_; ++t) {
        // -------- wait ----------------------------------------------------
        if (layer == 1) {
            // need producer h1[t] (prf >= t+1) and own h2[t-1] (myf >= t)
            for (;;) {
                int v2 = __hip_atomic_load(prf + (lane & 15), __ATOMIC_RELAXED, __HIP_MEMORY_SCOPE_AGENT);
                int ok = (v2 >= t + 1);
                if (t > 0) {
                    int v1 = __hip_atomic_load(myf + (lane & 15), __ATOMIC_RELAXED, __HIP_MEMORY_SCOPE_AGENT);
                    ok &= (v1 >= t);
                }
                if (__all(ok)) break;
                __builtin_amdgcn_s_sleep(1);
            }
        } else if (t > 0) {
            for (;;) {
                int v = __hip_atomic_load(myf + (lane & 15), __ATOMIC_RELAXED, __HIP_MEMORY_SCOPE_AGENT);
                if (__all(v >= t)) break;
                __builtin_amdgcn_s_sleep(1);
            }
        }
        asm volatile("" ::: "memory");   // no data-load hoisting above the spins

        // -------- operand loads (plain cached: L1-shared across 4 waves) --
        if (layer == 1) {   // x-side = h1[t], only readable post-flag
            const __hip_bfloat16* Ax = xin + ((unsigned long long)t * B_ + batch_base + n) * D_ + quad*8;
#pragma unroll
            for (int kt = 0; kt < 16; ++kt) axv[kt] = *(const bf16x8*)(Ax + kt*32);
        }
        const __hip_bfloat16* Ah = (t == 0)
            ? (zb + n * H_ + quad*8)
            : (hout + ((unsigned long long)(t-1) * B_ + batch_base + n) * H_ + quad*8);
        bf16x8 ah[16];
#pragma unroll
        for (int kt = 0; kt < 16; ++kt) ah[kt] = *(const bf16x8*)(Ah + kt*32);

        // -------- GEMM ----------------------------------------------------
        f32x4 acc0 = {0.f,0.f,0.f,0.f}, acc1 = {0.f,0.f,0.f,0.f};
#pragma unroll
        for (int kt = 0; kt < 16; ++kt) {
            acc0 = __builtin_amdgcn_mfma_f32_16x16x32_bf16(axv[kt], B0[kt], acc0, 0, 0, 0);
            acc1 = __builtin_amdgcn_mfma_f32_16x16x32_bf16(axv[kt], B1[kt], acc1, 0, 0, 0);
        }
#pragma unroll
        for (int kt = 0; kt < 16; ++kt) {
            acc0 = __builtin_amdgcn_mfma_f32_16x16x32_bf16(ah[kt], B0[16+kt], acc0, 0, 0, 0);
            acc1 = __builtin_amdgcn_mfma_f32_16x16x32_bf16(ah[kt], B1[16+kt], acc1, 0, 0, 0);
        }

        // -------- epilogue + publish h -----------------------------------
        float hv[4];
#pragma unroll
        for (int r = 0; r < 4; ++r) {
            float v0 = acc0[r] + bias0;          // i | o pre-activation
            float v1 = acc1[r] + bias1;          // f | u pre-activation
            float act0 = 1.f / (1.f + __expf(-v0));        // sigmoid (i and o)
            float pre  = (n < 8) ? -v1 : -2.f*v1;
            float s    = 1.f / (1.f + __expf(pre));
            float act1 = (n < 8) ? s : (2.f*s - 1.f);      // f: sigmoid, u: tanh=2σ(2x)-1
            float o_ = __shfl_xor(act0, 8);      // lanes n<8 receive sigmoid(o)
            float u_ = __shfl_xor(act1, 8);      // lanes n<8 receive tanh(u)
            float ci = act1 * cst[r] + act0 * u_;              // f*c + i*u
            float ni = fminf(fmaxf(act1 * nst[r] + act0, 1e-6f), 1e6f);
            cst[r] = ci; nst[r] = ni;
            float ratio = ci / ni;               // |ratio| <= 1 by induction
            float e2 = __expf(-2.f * ratio);
            float th = (1.f - e2) / (1.f + e2);  // tanh(ratio)
            hv[r] = o_ * th;

            // pack bf16 pair (hid n, n+1) into u32, sc1 write-through store
            unsigned mybits = bf16_bits(hv[r]);
            unsigned other  = (unsigned)__shfl_xor((int)mybits, 1);
            if ((n & 1) == 0 && n < 8) {
                const int b = batch_base + quad*4 + r;
                unsigned pack = (mybits & 0xffffu) | (other << 16);
                unsigned* p = (unsigned*)(hout + ((unsigned long long)t * B_ + b) * H_ + hid_base + n);
                __hip_atomic_store(p, pack, __ATOMIC_RELAXED, __HIP_MEMORY_SCOPE_AGENT);
            }
        }

        if (n < 8) {
            const int hid = hid_base + n;
            if (layer == 1) {
#pragma unroll
                for (int r = 0; r < 4; ++r) {
                    const int b = batch_base + quad*4 + r;
                    out[((unsigned long long)b * T_ + t) * H_ + hid] = hv[r];  // plain (kernel-end flush)
                }
            }
            if (t == T_ - 1) {
#pragma unroll
                for (int r = 0; r < 4; ++r) {
                    const int b = batch_base + quad*4 + r;
                    unsigned long long so = OUT_HN + (unsigned long long)layer*32768ull
                                          + (unsigned long long)b*H_ + hid;
                    out[so]            = hv[r];   // hN
                    out[so +  65536ull] = cst[r]; // cN
                    out[so + 131072ull] = nst[r]; // nN
                }
            }
        }

        // -------- x prefetch for t+1 (layer0: static data) ---------------
        // issued before the barrier so its latency overlaps the store-ack drain
        if (layer == 0 && t + 1 < T_) {
            const __hip_bfloat16* Axn = xin + ((unsigned long long)(t+1) * B_ + batch_base + n) * D_ + quad*8;
#pragma unroll
            for (int kt = 0; kt < 16; ++kt) axv[kt] = *(const bf16x8*)(Axn + kt*32);
        }

        // -------- arrive --------------------------------------------------
        // explicit vmcnt(0) drain (merges with the compiler's own barrier
        // drain) -> s_barrier -> tid0 publishes the flag: all 4 waves' sc1
        // h-stores are L3-acked before the flag becomes visible.
        asm volatile("s_waitcnt vmcnt(0)" ::: "memory");
        __syncthreads();
        if (tid == 0)
            __hip_atomic_store(myf + w2, t + 1, __ATOMIC_RELAXED, __HIP_MEMORY_SCOPE_AGENT);
    }
}

extern "C" void kernel_launch(void* const* d_in, const int* in_sizes, int n_in,
                              void* d_out, int out_size, void* d_ws, size_t ws_size,
                              hipStream_t stream)
{
    const float* x    = (const float*)d_in[0];
    const float* Wx   = (const float*)d_in[1];
    const float* bx   = (const float*)d_in[2];
    const float* Wh   = (const float*)d_in[3];
    const float* bh   = (const float*)d_in[4];
    const float* bext = (const float*)d_in[5];
    float* out = (float*)d_out;
    unsigned char* ws = (unsigned char*)d_ws;
    // needs ~200 MiB of workspace (xT 64M + h1 64M + h2 64M + W' 8M + misc)

    prep_kernel<<<16384, 256, 0, stream>>>(x, Wx, Wh, ws);
    slstm_persist<<<128, 256, 0, stream>>>(bx, bh, bext, ws, out);
}